// Round 1
// baseline (1371.990 us; speedup 1.0000x reference)
//
#include <hip/hip_runtime.h>
#include <hip/hip_bf16.h>

#define N_TOK 16384
#define DIM   1024
#define NEXP  4
#define HID   4096

typedef __attribute__((ext_vector_type(8))) short short8;
typedef __attribute__((ext_vector_type(4))) short short4v;
typedef __attribute__((ext_vector_type(4))) float float4v;

static __device__ __forceinline__ short f2bf(float f) {
  __hip_bfloat16 h = __float2bfloat16(f);
  return *reinterpret_cast<short*>(&h);
}

#define GLOAD_LDS16(gsrc, ldst)                                                            \
  __builtin_amdgcn_global_load_lds((const __attribute__((address_space(1))) void*)(gsrc),  \
                                   (__attribute__((address_space(3))) void*)(ldst), 16, 0, 0)

// ---------------- gate: softmax(concat(q,k) @ Wg + bg) ----------------
__global__ void gate_kernel(const float* __restrict__ q, const float* __restrict__ k,
                            const float* __restrict__ Wg, const float* __restrict__ bg,
                            float* __restrict__ gate) {
  const int wave = threadIdx.x >> 6, lane = threadIdx.x & 63;
  const int n = blockIdx.x * 4 + wave;
  const float* qr = q + (size_t)n * DIM;
  const float* kr = k + (size_t)n * DIM;
  float s0 = 0.f, s1 = 0.f, s2 = 0.f, s3 = 0.f;
  for (int i = 0; i < DIM / 64; ++i) {
    int d = i * 64 + lane;
    float x = qr[d];
    float4 w = *(const float4*)(Wg + (size_t)d * 4);
    s0 += x * w.x; s1 += x * w.y; s2 += x * w.z; s3 += x * w.w;
    float y = kr[d];
    float4 w2 = *(const float4*)(Wg + (size_t)(DIM + d) * 4);
    s0 += y * w2.x; s1 += y * w2.y; s2 += y * w2.z; s3 += y * w2.w;
  }
  for (int off = 32; off; off >>= 1) {
    s0 += __shfl_xor(s0, off);
    s1 += __shfl_xor(s1, off);
    s2 += __shfl_xor(s2, off);
    s3 += __shfl_xor(s3, off);
  }
  if (lane == 0) {
    float l0 = s0 + bg[0], l1 = s1 + bg[1], l2 = s2 + bg[2], l3 = s3 + bg[3];
    // TEMP == 1.0
    float m = fmaxf(fmaxf(l0, l1), fmaxf(l2, l3));
    float e0 = expf(l0 - m), e1 = expf(l1 - m), e2 = expf(l2 - m), e3 = expf(l3 - m);
    float inv = 1.f / (e0 + e1 + e2 + e3);
    float4 g; g.x = e0 * inv; g.y = e1 * inv; g.z = e2 * inv; g.w = e3 * inv;
    *(float4*)(gate + (size_t)n * 4) = g;
  }
}

// ---------------- f32 -> bf16 straight convert (vectorized) ----------------
__global__ void convert_bf16_kernel(const float* __restrict__ in, short* __restrict__ out, int n4) {
  int stride = gridDim.x * blockDim.x;
  for (int i = blockIdx.x * blockDim.x + threadIdx.x; i < n4; i += stride) {
    float4 v = *(const float4*)(in + (size_t)i * 4);
    short4v o;
    o[0] = f2bf(v.x); o[1] = f2bf(v.y); o[2] = f2bf(v.z); o[3] = f2bf(v.w);
    *(short4v*)(out + (size_t)i * 4) = o;
  }
}

// ---------------- LDS-tiled transpose + convert: in[R][C] f32 -> out[C][R] bf16 ----------------
__global__ void transpose_bf16_kernel(const float* __restrict__ in, short* __restrict__ out,
                                      int R, int C) {
  __shared__ float tile[64][65];
  const size_t eoff = (size_t)blockIdx.z * (size_t)R * C;
  const float* src = in + eoff;
  short* dst = out + eoff;
  const int r0 = blockIdx.y * 64, c0 = blockIdx.x * 64;
  const int tc = threadIdx.x & 63, tr = threadIdx.x >> 6;
#pragma unroll
  for (int p = 0; p < 16; ++p) {
    int r = p * 4 + tr;
    tile[r][tc] = src[(size_t)(r0 + r) * C + (c0 + tc)];
  }
  __syncthreads();
#pragma unroll
  for (int p = 0; p < 16; ++p) {
    int i = p * 4 + tr;  // column index within tile -> output row
    dst[(size_t)(c0 + i) * R + (r0 + tc)] = f2bf(tile[tc][i]);
  }
}

// ---------------- bf16 MFMA GEMM: C = A[M,K] @ Bt[N,K]^T, 128x128 tile, BK=64 ----------------
// MODE 1: Hs[row,col] = bf16( gate[row] * relu(C + b1[col]) )
// MODE 2: Out[row,col] (+)= C + gate[row]*b2[col]
template <int MODE>
__global__ __launch_bounds__(256, 2)
void gemm_kernel(const short* __restrict__ A, const short* __restrict__ Bt, int K,
                 const float* __restrict__ bias, const float* __restrict__ gate4,
                 short* __restrict__ HsOut, float* __restrict__ FOut, int ldc, int accumulate) {
  __shared__ short sA[128 * 64];
  __shared__ short sB[128 * 64];
  const int t = threadIdx.x;
  const int m0 = blockIdx.y * 128;
  const int n0 = blockIdx.x * 128;
  const int lane = t & 63;
  const int wave = t >> 6;
  const int wm = (wave >> 1) * 64;
  const int wn = (wave & 1) * 64;
  const int r16 = lane & 15;
  const int kg = lane >> 4;

  float4v acc[4][4];
#pragma unroll
  for (int m = 0; m < 4; ++m)
#pragma unroll
    for (int n = 0; n < 4; ++n) acc[m][n] = (float4v)0.0f;

  for (int k0 = 0; k0 < K; k0 += 64) {
    // stage A/B tiles: linear LDS dest, inverse-swizzled global source (rule #21)
#pragma unroll
    for (int i = 0; i < 4; ++i) {
      int c = i * 256 + t;
      int row = c >> 3;
      int jc = (c & 7) ^ (row & 7);
      GLOAD_LDS16(A + (size_t)(m0 + row) * K + k0 + jc * 8, &sA[c * 8]);
      GLOAD_LDS16(Bt + (size_t)(n0 + row) * K + k0 + jc * 8, &sB[c * 8]);
    }
    __syncthreads();  // drains vmcnt: staged data visible
#pragma unroll
    for (int kk = 0; kk < 2; ++kk) {
      short8 af[4], bfr[4];
#pragma unroll
      for (int m = 0; m < 4; ++m) {
        int row = wm + m * 16 + r16;
        int jc = (kk * 4 + kg) ^ (row & 7);
        af[m] = *(const short8*)&sA[row * 64 + jc * 8];
      }
#pragma unroll
      for (int n = 0; n < 4; ++n) {
        int row = wn + n * 16 + r16;
        int jc = (kk * 4 + kg) ^ (row & 7);
        bfr[n] = *(const short8*)&sB[row * 64 + jc * 8];
      }
#pragma unroll
      for (int m = 0; m < 4; ++m)
#pragma unroll
        for (int n = 0; n < 4; ++n)
          acc[m][n] = __builtin_amdgcn_mfma_f32_16x16x32_bf16(af[m], bfr[n], acc[m][n], 0, 0, 0);
    }
    __syncthreads();  // all ds_reads done before next stage overwrites
  }

  // epilogue: C/D layout col = lane&15, row = (lane>>4)*4 + reg  [m89/m91]
#pragma unroll
  for (int m = 0; m < 4; ++m) {
    int rbase = m0 + wm + m * 16 + kg * 4;
#pragma unroll
    for (int n = 0; n < 4; ++n) {
      int col = n0 + wn + n * 16 + r16;
      float bcol = bias[col];
#pragma unroll
      for (int r = 0; r < 4; ++r) {
        int grow = rbase + r;
        float g = gate4[(size_t)grow * 4];
        float v = acc[m][n][r];
        if (MODE == 1) {
          v += bcol;
          v = fmaxf(v, 0.f);
          v *= g;
          HsOut[(size_t)grow * ldc + col] = f2bf(v);
        } else {
          v += g * bcol;
          size_t oi = (size_t)grow * ldc + col;
          if (accumulate) v += FOut[oi];
          FOut[oi] = v;
        }
      }
    }
  }
}

extern "C" void kernel_launch(void* const* d_in, const int* in_sizes, int n_in,
                              void* d_out, int out_size, void* d_ws, size_t ws_size,
                              hipStream_t stream) {
  const float* q  = (const float*)d_in[0];
  const float* k  = (const float*)d_in[1];
  const float* W1 = (const float*)d_in[2];
  const float* b1 = (const float*)d_in[3];
  const float* W2 = (const float*)d_in[4];
  const float* b2 = (const float*)d_in[5];
  const float* Wg = (const float*)d_in[6];
  const float* bg = (const float*)d_in[7];
  float* out = (float*)d_out;

  char* ws = (char*)d_ws;
  size_t off = 0;
  float* gate = (float*)(ws + off); off += (size_t)N_TOK * 4 * sizeof(float);
  short* qb   = (short*)(ws + off); off += (size_t)N_TOK * DIM * 2;
  short* W1t  = (short*)(ws + off); off += (size_t)NEXP * (size_t)DIM * HID * 2;
  short* W2t  = (short*)(ws + off); off += (size_t)NEXP * (size_t)HID * DIM * 2;
  short* Hs   = (short*)(ws + off);

  size_t avail = (ws_size > off) ? (ws_size - off) : 0;
  long long mc = (long long)(avail / ((size_t)HID * 2));
  mc &= ~127LL;
  if (mc < 128) mc = 128;          // minimum viable chunk
  if (mc > N_TOK) mc = N_TOK;
  const int max_chunk = (int)mc;

  gate_kernel<<<dim3(N_TOK / 4), dim3(256), 0, stream>>>(q, k, Wg, bg, gate);
  convert_bf16_kernel<<<dim3(2048), dim3(256), 0, stream>>>(q, qb, N_TOK * DIM / 4);
  transpose_bf16_kernel<<<dim3(HID / 64, DIM / 64, NEXP), dim3(256), 0, stream>>>(W1, W1t, DIM, HID);
  transpose_bf16_kernel<<<dim3(DIM / 64, HID / 64, NEXP), dim3(256), 0, stream>>>(W2, W2t, HID, DIM);

  for (int cb = 0; cb < N_TOK; cb += max_chunk) {
    int rows = (N_TOK - cb < max_chunk) ? (N_TOK - cb) : max_chunk;
    for (int e = 0; e < NEXP; ++e) {
      gemm_kernel<1><<<dim3(HID / 128, rows / 128), dim3(256), 0, stream>>>(
          qb + (size_t)cb * DIM, W1t + (size_t)e * HID * DIM, DIM,
          b1 + (size_t)e * HID, gate + (size_t)cb * 4 + e,
          Hs, (float*)nullptr, HID, 0);
      gemm_kernel<2><<<dim3(DIM / 128, rows / 128), dim3(256), 0, stream>>>(
          Hs, W2t + (size_t)e * DIM * HID, HID,
          b2 + (size_t)e * DIM, gate + (size_t)cb * 4 + e,
          (short*)nullptr, out + (size_t)cb * DIM, DIM, e > 0);
    }
  }
}